// Round 5
// baseline (55.474 us; speedup 1.0000x reference)
//
#include <hip/hip_runtime.h>
#include <hip/hip_bf16.h>

// Problem constants (from reference setup_inputs)
#define NB 8192   // batch
#define NH 8      // heads
#define ND 512    // D
#define NO 256    // DO
#define ROWS 16   // batch rows per block
#define TPB 512   // threads per block (8 waves)
#define SROWS 4   // rows per DMA stage
#define NSTEP 4   // ROWS / SROWS
#define STAGE_FLOATS (SROWS * NH * ND)   // 16384 floats = 64 KB per buffer

typedef __attribute__((ext_vector_type(8))) short short8;
typedef __attribute__((ext_vector_type(4))) float f32x4;

// W converted to bf16 once per launch (256 KB, L2-resident during GEMM phase)
__device__ __align__(16) ushort g_wb[NO * ND];

__device__ __forceinline__ ushort f2bf(float f) {
    union { float f; unsigned u; } v; v.f = f;
    unsigned u = v.u;
    unsigned r = u + 0x7FFFu + ((u >> 16) & 1u);   // round-to-nearest-even
    return (ushort)(r >> 16);
}

__global__ __launch_bounds__(256) void wcvt_kernel(const float* __restrict__ W) {
    int i = (blockIdx.x * 256 + threadIdx.x) * 4;
    float4 w = *(const float4*)(W + i);
    ushort4 o;
    o.x = f2bf(w.x); o.y = f2bf(w.y); o.z = f2bf(w.z); o.w = f2bf(w.w);
    *(ushort4*)(g_wb + i) = o;
}

__device__ __forceinline__ float swishf(float h) {
    // h * sigmoid(h); overflow-safe: h<<0 -> exp(-h)=inf -> rcp=0 -> -0
    return h * __builtin_amdgcn_rcpf(1.0f + __expf(-h));
}

__device__ __forceinline__ void gl_lds16(const void* g, void* l) {
    __builtin_amdgcn_global_load_lds(
        (const __attribute__((address_space(1))) void*)g,
        (__attribute__((address_space(3))) void*)l, 16, 0, 0);
}

__global__ __launch_bounds__(TPB) void fused_kernel(
    const float* __restrict__ x, const float* __restrict__ rw,
    const float* __restrict__ gamma, const float* __restrict__ beta,
    const float* __restrict__ mean, const float* __restrict__ var,
    const float* __restrict__ bias, float* __restrict__ out)
{
    // DMA-staged x tiles (linear layout: required by global_load_lds)
    __shared__ __align__(16) float xs[2][STAGE_FLOATS];   // 2 x 64 KB
    // y-tile: ROWS x ND bf16, row pitch 1024 B, XOR-swizzled within row
    __shared__ __align__(16) ushort yl[ROWS * ND];        // 16 KB
    __shared__ float rwl[ROWS * NH];                      // 512 B

    const int tid = threadIdx.x;
    const int b0  = blockIdx.x * ROWS;

    // ---------------- prologue: params + rw to LDS (normal loads) ----------------
    const int d4  = tid & 127;
    const int row = tid >> 7;      // 0..3 (row within stage)
    const int d   = d4 * 4;

    if (tid < 32)
        ((float4*)rwl)[tid] = ((const float4*)(rw + (size_t)b0 * NH))[tid];

    float4 g4 = *(const float4*)(gamma + d);
    float4 v4 = *(const float4*)(var   + d);
    float4 be = *(const float4*)(beta  + d);
    float4 me = *(const float4*)(mean  + d);
    const float ix = g4.x * rsqrtf(v4.x + 1e-5f);
    const float iy = g4.y * rsqrtf(v4.y + 1e-5f);
    const float iz = g4.z * rsqrtf(v4.z + 1e-5f);
    const float iw = g4.w * rsqrtf(v4.w + 1e-5f);
    const float ox = be.x - me.x * ix;
    const float oy = be.y - me.y * iy;
    const float oz = be.z - me.z * iz;
    const float ow = be.w - me.w * iw;

    __syncthreads();   // full drain: vmcnt clean before counted DMA pipeline

    // ---------------- DMA staging helper: 64 KB contiguous tile ----------------
    const char* xbase = (const char*)(x + (size_t)b0 * (NH * ND));
    #define STAGE(s, b) do {                                              \
        const char* _src = xbase + (size_t)(s) * (SROWS * NH * ND * 4);   \
        char* _dst = (char*)&xs[b][0];                                    \
        _Pragma("unroll")                                                 \
        for (int _r = 0; _r < 8; ++_r) {                                  \
            const int _off = _r * 8192 + tid * 16;                        \
            gl_lds16(_src + _off, _dst + _off);                           \
        }                                                                 \
    } while (0)

    STAGE(0, 0);
    STAGE(1, 1);

    // ---------------- pipelined phase 1: 4 steps x 4 rows ----------------
    #pragma unroll
    for (int s = 0; s < NSTEP; ++s) {
        const int cur = s & 1;
        if (s < NSTEP - 1) asm volatile("s_waitcnt vmcnt(8)" ::: "memory");
        else               asm volatile("s_waitcnt vmcnt(0)" ::: "memory");
        __builtin_amdgcn_s_barrier();
        asm volatile("" ::: "memory");

        const int rr = s * SROWS + row;
        const float* xr = xs[cur] + row * (NH * ND) + d;
        float whv[NH];
        #pragma unroll
        for (int h = 0; h < NH; ++h) whv[h] = rwl[rr * NH + h];

        float ax = 0.f, ay = 0.f, az = 0.f, aw = 0.f;
        #pragma unroll
        for (int h = 0; h < NH; ++h) {
            float4 xa = *(const float4*)(xr + h * ND);
            const float wh = whv[h];
            ax += wh * swishf(xa.x * ix + ox);
            ay += wh * swishf(xa.y * iy + oy);
            az += wh * swishf(xa.z * iz + oz);
            aw += wh * swishf(xa.w * iw + ow);
        }
        const int addr = rr * 1024 + ((d * 2) ^ ((rr & 7) << 4));
        ushort4 o;
        o.x = f2bf(ax); o.y = f2bf(ay); o.z = f2bf(az); o.w = f2bf(aw);
        *(ushort4*)((char*)yl + addr) = o;

        asm volatile("s_waitcnt lgkmcnt(0)" ::: "memory");
        __builtin_amdgcn_s_barrier();
        asm volatile("" ::: "memory");

        if (s + 2 < NSTEP) STAGE(s + 2, cur);   // refill the buffer just freed
    }
    #undef STAGE

    // ---------------- phase 2: [16 x 512] @ W^T via bf16 MFMA ----------------
    // 8 waves, each owns 32 output cols (2 n-fragments of 16)
    const int lane = tid & 63;
    const int wv   = tid >> 6;           // 0..7
    const int n0   = wv * 32;
    const int lr   = lane & 15;          // A-row / B-col-within-frag
    const int lk   = (lane >> 4) * 8;    // k offset within 32

    f32x4 acc0 = {0.f, 0.f, 0.f, 0.f};
    f32x4 acc1 = {0.f, 0.f, 0.f, 0.f};

    const char* ylb = (const char*)yl + lr * 1024;
    const int swz = (lr & 7) << 4;

    #pragma unroll 4
    for (int ks = 0; ks < 16; ++ks) {
        const int k0 = ks * 32;
        const int kb = (k0 + lk) * 2;
        short8 a = *(const short8*)(ylb + (kb ^ swz));
        const ushort* wp = g_wb + (size_t)(n0 + lr) * ND + k0 + lk;
        short8 bf0 = *(const short8*)(wp);
        short8 bf1 = *(const short8*)(wp + 16 * ND);
        acc0 = __builtin_amdgcn_mfma_f32_16x16x32_bf16(a, bf0, acc0, 0, 0, 0);
        acc1 = __builtin_amdgcn_mfma_f32_16x16x32_bf16(a, bf1, acc1, 0, 0, 0);
    }

    // epilogue: D layout col = lane&15, row = (lane>>4)*4 + reg
    const int rbase = (lane >> 4) * 4;
    float sw[4];
    #pragma unroll
    for (int q = 0; q < 4; ++q) {
        const float* rp = rwl + (rbase + q) * NH;
        sw[q] = ((rp[0] + rp[1]) + (rp[2] + rp[3])) +
                ((rp[4] + rp[5]) + (rp[6] + rp[7]));
    }
    f32x4 accs[2] = {acc0, acc1};
    #pragma unroll
    for (int nf = 0; nf < 2; ++nf) {
        const int col = n0 + nf * 16 + lr;
        const float bn = bias[col];
        #pragma unroll
        for (int q = 0; q < 4; ++q) {
            const int r = rbase + q;
            out[(size_t)(b0 + r) * NO + col] = accs[nf][q] + bn * sw[q];
        }
    }
}

extern "C" void kernel_launch(void* const* d_in, const int* in_sizes, int n_in,
                              void* d_out, int out_size, void* d_ws, size_t ws_size,
                              hipStream_t stream) {
    const float* x     = (const float*)d_in[0];
    const float* rw    = (const float*)d_in[1];
    const float* gamma = (const float*)d_in[2];
    const float* beta  = (const float*)d_in[3];
    const float* mean  = (const float*)d_in[4];
    const float* var   = (const float*)d_in[5];
    const float* W     = (const float*)d_in[6];
    const float* bias  = (const float*)d_in[7];
    float* out = (float*)d_out;

    hipLaunchKernelGGL(wcvt_kernel, dim3((NO * ND) / 1024), dim3(256), 0, stream, W);
    hipLaunchKernelGGL(fused_kernel, dim3(NB / ROWS), dim3(TPB), 0, stream,
                       x, rw, gamma, beta, mean, var, bias, out);
}

// Round 10
// 47.958 us; speedup vs baseline: 1.1567x; 1.1567x over previous
//
#include <hip/hip_runtime.h>
#include <hip/hip_bf16.h>

// Problem constants (from reference setup_inputs)
#define NB 8192   // batch
#define NH 8      // heads
#define ND 512    // D
#define NO 256    // DO
#define ROWS 16   // batch rows per block
#define TPB 512   // threads per block (8 waves)

typedef __attribute__((ext_vector_type(8))) short short8;
typedef __attribute__((ext_vector_type(4))) float f32x4;

// W converted to bf16 once per launch (256 KB, L2-resident during GEMM phase)
__device__ __align__(16) ushort g_wb[NO * ND];

__device__ __forceinline__ ushort f2bf(float f) {
    union { float f; unsigned u; } v; v.f = f;
    unsigned u = v.u;
    unsigned r = u + 0x7FFFu + ((u >> 16) & 1u);   // round-to-nearest-even
    return (ushort)(r >> 16);
}

__global__ __launch_bounds__(256) void wcvt_kernel(const float* __restrict__ W) {
    int i = (blockIdx.x * 256 + threadIdx.x) * 4;
    float4 w = *(const float4*)(W + i);
    ushort4 o;
    o.x = f2bf(w.x); o.y = f2bf(w.y); o.z = f2bf(w.z); o.w = f2bf(w.w);
    *(ushort4*)(g_wb + i) = o;
}

__device__ __forceinline__ float swishf(float h) {
    // h * sigmoid(h); overflow-safe: h<<0 -> exp(-h)=inf -> rcp=0 -> -0
    return h * __builtin_amdgcn_rcpf(1.0f + __expf(-h));
}

__global__ __launch_bounds__(TPB) void fused_kernel(
    const float* __restrict__ x, const float* __restrict__ rw,
    const float* __restrict__ gamma, const float* __restrict__ beta,
    const float* __restrict__ mean, const float* __restrict__ var,
    const float* __restrict__ bias, float* __restrict__ out)
{
    // y-tile: ROWS x ND bf16, row pitch 1024 B, XOR-swizzled within row
    __shared__ __align__(16) ushort yl[ROWS * ND];   // 16 KB
    __shared__ float rwl[ROWS * NH];                 // 512 B

    const int tid = threadIdx.x;
    const int b0  = blockIdx.x * ROWS;
    const int d4  = tid & 127;        // d-chunk (float4 index)
    const int rh  = tid >> 7;         // 0..3: thread owns rows rh, rh+4, rh+8, rh+12
    const int d   = d4 * 4;

    if (tid < 32)
        ((float4*)rwl)[tid] = ((const float4*)(rw + (size_t)b0 * NH))[tid];

    float4 g4 = *(const float4*)(gamma + d);
    float4 v4 = *(const float4*)(var   + d);
    float4 be = *(const float4*)(beta  + d);
    float4 me = *(const float4*)(mean  + d);
    const float ix = g4.x * rsqrtf(v4.x + 1e-5f);
    const float iy = g4.y * rsqrtf(v4.y + 1e-5f);
    const float iz = g4.z * rsqrtf(v4.z + 1e-5f);
    const float iw = g4.w * rsqrtf(v4.w + 1e-5f);
    const float ox = be.x - me.x * ix;
    const float oy = be.y - me.y * iy;
    const float oz = be.z - me.z * iz;
    const float ow = be.w - me.w * iw;

    __syncthreads();   // rwl visible to all

    // ---------------- phase 1: straight-line software pipeline ----------------
    // 4 row-buffers of 8 float4 (compile-time indexed after unroll -> registers).
    // Issue order pinned with sched_barrier(0); waits are compiler-inserted
    // (correct by construction).
    float4 L0[NH], L1[NH], L2[NH], L3[NH];

#define ISSUE(Lb, rr) do {                                                  \
    const float* _xr = x + (size_t)(b0 + (rr)) * (NH * ND) + d;             \
    _Pragma("unroll")                                                       \
    for (int h = 0; h < NH; ++h) Lb[h] = *(const float4*)(_xr + h * ND);    \
} while (0)

#define COMPUTE(Lb, rr) do {                                                \
    const float4 _w0 = ((const float4*)(rwl + (rr) * NH))[0];               \
    const float4 _w1 = ((const float4*)(rwl + (rr) * NH))[1];               \
    const float _whv[NH] = {_w0.x,_w0.y,_w0.z,_w0.w,_w1.x,_w1.y,_w1.z,_w1.w};\
    float ax = 0.f, ay = 0.f, az = 0.f, aw = 0.f;                           \
    _Pragma("unroll")                                                       \
    for (int h = 0; h < NH; ++h) {                                          \
        const float _wh = _whv[h];                                          \
        ax += _wh * swishf(Lb[h].x * ix + ox);                              \
        ay += _wh * swishf(Lb[h].y * iy + oy);                              \
        az += _wh * swishf(Lb[h].z * iz + oz);                              \
        aw += _wh * swishf(Lb[h].w * iw + ow);                              \
    }                                                                       \
    const int _addr = (rr) * 1024 + ((d4 * 8) ^ (((rr) & 7) << 4));         \
    ushort4 _o;                                                             \
    _o.x = f2bf(ax); _o.y = f2bf(ay); _o.z = f2bf(az); _o.w = f2bf(aw);     \
    *(ushort4*)((char*)yl + _addr) = _o;                                    \
} while (0)

    ISSUE(L0, rh);
    ISSUE(L1, rh + 4);
    __builtin_amdgcn_sched_barrier(0);

    COMPUTE(L0, rh);          // waits only on L0's 8 loads; L1 stays in flight
    ISSUE(L2, rh + 8);
    __builtin_amdgcn_sched_barrier(0);

    COMPUTE(L1, rh + 4);
    ISSUE(L3, rh + 12);
    __builtin_amdgcn_sched_barrier(0);

    COMPUTE(L2, rh + 8);
    __builtin_amdgcn_sched_barrier(0);

    COMPUTE(L3, rh + 12);

#undef ISSUE
#undef COMPUTE

    __syncthreads();

    // ---------------- phase 2: [16 x 512] @ W^T via bf16 MFMA ----------------
    // 8 waves, each owns 32 output cols (2 n-fragments of 16)
    const int lane = tid & 63;
    const int wv   = tid >> 6;           // 0..7
    const int n0   = wv * 32;
    const int lr   = lane & 15;          // A-row / B-col-within-frag
    const int lk   = (lane >> 4) * 8;    // k offset within 32

    f32x4 acc0 = {0.f, 0.f, 0.f, 0.f};
    f32x4 acc1 = {0.f, 0.f, 0.f, 0.f};

    const char* ylb = (const char*)yl + lr * 1024;
    const int swz = (lr & 7) << 4;

    #pragma unroll 4
    for (int ks = 0; ks < 16; ++ks) {
        const int k0 = ks * 32;
        const int kb = (k0 + lk) * 2;
        short8 a = *(const short8*)(ylb + (kb ^ swz));
        const ushort* wp = g_wb + (size_t)(n0 + lr) * ND + k0 + lk;
        short8 bf0 = *(const short8*)(wp);
        short8 bf1 = *(const short8*)(wp + 16 * ND);
        acc0 = __builtin_amdgcn_mfma_f32_16x16x32_bf16(a, bf0, acc0, 0, 0, 0);
        acc1 = __builtin_amdgcn_mfma_f32_16x16x32_bf16(a, bf1, acc1, 0, 0, 0);
    }

    // epilogue: D layout col = lane&15, row = (lane>>4)*4 + reg
    const int rbase = (lane >> 4) * 4;
    float sw[4];
    #pragma unroll
    for (int q = 0; q < 4; ++q) {
        const float* rp = rwl + (rbase + q) * NH;
        sw[q] = ((rp[0] + rp[1]) + (rp[2] + rp[3])) +
                ((rp[4] + rp[5]) + (rp[6] + rp[7]));
    }
    f32x4 accs[2] = {acc0, acc1};
    #pragma unroll
    for (int nf = 0; nf < 2; ++nf) {
        const int col = n0 + nf * 16 + lr;
        const float bn = bias[col];
        #pragma unroll
        for (int q = 0; q < 4; ++q) {
            const int r = rbase + q;
            out[(size_t)(b0 + r) * NO + col] = accs[nf][q] + bn * sw[q];
        }
    }
}

extern "C" void kernel_launch(void* const* d_in, const int* in_sizes, int n_in,
                              void* d_out, int out_size, void* d_ws, size_t ws_size,
                              hipStream_t stream) {
    const float* x     = (const float*)d_in[0];
    const float* rw    = (const float*)d_in[1];
    const float* gamma = (const float*)d_in[2];
    const float* beta  = (const float*)d_in[3];
    const float* mean  = (const float*)d_in[4];
    const float* var   = (const float*)d_in[5];
    const float* W     = (const float*)d_in[6];
    const float* bias  = (const float*)d_in[7];
    float* out = (float*)d_out;

    hipLaunchKernelGGL(wcvt_kernel, dim3((NO * ND) / 1024), dim3(256), 0, stream, W);
    hipLaunchKernelGGL(fused_kernel, dim3(NB / ROWS), dim3(TPB), 0, stream,
                       x, rw, gamma, beta, mean, var, bias, out);
}